// Round 3
// baseline (324.694 us; speedup 1.0000x reference)
//
#include <hip/hip_runtime.h>

// ---- workspace layout (bytes) ----
#define IDENTP_OFF 0u            // identp: 8*3*98*100*2 = 470400
#define HMP_OFF    470400u       // hmp: 256*98*100*2 = 5017600
#define ACT1CL_OFF 5488000u      // act1cl: 256*50*52*64*2 = 85196800 (ends 90684800)
#define ACT3P_OFF  470400u       // act3p: 256*50*50*64*2 = 81920000 — aliases hmp+act1cl (dead after conv2)
#define ACT2P_OFF  90684800u     // act2p: 256*26*26*128*2 = 44302336
#define W2B_OFF    134987136u    // w2t: [32 kk][128n*32el] = 262144
#define W3B_OFF    135249280u    // w3c: [4 cls][16 kk][64n][32e linear] = 262144
#define W1B_OFF    135642496u    // w1b: 64*64*2 = 8192
#define W4C_OFF    135650688u    // w4c: 16*576*2 = 18432

using short8  = __attribute__((ext_vector_type(8))) short;
using floatx4 = __attribute__((ext_vector_type(4))) float;
union UV { uint4 u; short8 s; };

static __device__ __forceinline__ float bf2f(unsigned short u) {
  union { unsigned int i; float f; } v; v.i = ((unsigned int)u) << 16; return v.f;
}
static __device__ __forceinline__ unsigned short f2bf(float f) {
  union { float f; unsigned int i; } v; v.f = f;
  unsigned int x = v.i;
  return (unsigned short)((x + 0x7FFFu + ((x >> 16) & 1u)) >> 16);  // RNE
}
static __device__ __forceinline__ uint4 pack8(const unsigned short* v) {
  uint4 p;
  p.x = (unsigned)v[0] | ((unsigned)v[1] << 16);
  p.y = (unsigned)v[2] | ((unsigned)v[3] << 16);
  p.z = (unsigned)v[4] | ((unsigned)v[5] << 16);
  p.w = (unsigned)v[6] | ((unsigned)v[7] << 16);
  return p;
}
static __device__ __forceinline__ float ftanh(float x) {
  x = fminf(fmaxf(x, -10.f), 10.f);
  float e = __expf(2.f * x);
  return (e - 1.f) * __builtin_amdgcn_rcpf(e + 1.f);
}

// ============ prep ============
__global__ __launch_bounds__(256) void prep_kernel(
    const float* __restrict__ lm, const float* __restrict__ ident,
    const float* __restrict__ w1, const float* __restrict__ w2,
    const float* __restrict__ w3, const float* __restrict__ w4,
    unsigned short* __restrict__ identp, unsigned short* __restrict__ hmp,
    unsigned short* __restrict__ w1b, unsigned short* __restrict__ w2t,
    unsigned short* __restrict__ w3c, unsigned short* __restrict__ w4c,
    unsigned short* __restrict__ act1cl, unsigned short* __restrict__ act2p) {
  int bid = blockIdx.x, tid = threadIdx.x;
  if (bid < 256) {
    // hmp [bt][98][100]
    unsigned int* h32 = (unsigned int*)(hmp + bid * 9800);
    for (int i = tid; i < 4900; i += 256) h32[i] = 0u;
    __syncthreads();
    if (tid < 68) {
      float x = lm[bid * 136 + tid * 2 + 0] * 95.0f;
      float y = lm[bid * 136 + tid * 2 + 1] * 95.0f;
      int ix = (int)x, iy = (int)y;
      if (ix >= 0 && ix < 96 && iy >= 0 && iy < 96)
        hmp[bid * 9800 + (iy + 1) * 100 + (ix + 1)] = 0x3F80;
    }
  } else if (bid < 320) {
    // w2t [kk32][n128*32el]: element (kk,n,e): k'=kk*32+e, k'=tap*64+ic
    int idx = (bid - 256) * 2048 + tid * 8;
    int kk = idx >> 12, rem = idx & 4095;
    int n = rem >> 5, e = rem & 31;
    unsigned short v[8];
#pragma unroll
    for (int j = 0; j < 8; j++) {
      int t = kk * 32 + e + j;
      int tap = t >> 6, ic = t & 63;
      v[j] = f2bf(w2[n * 1024 + ic * 16 + tap]);
    }
    *(uint4*)(w2t + idx) = pack8(v);
  } else if (bid < 384) {
    // w3c [4 cls][16 kk][64 n][32 e] LINEAR: k = kk*32+e; tap=k>>7 (dh=tap>>1,dw=tap&1); ic=k&127
    //   kh = 3 - r - 2*dh, kw = 3 - s - 2*dw   (all taps valid -> zero-free)
    int idx = (bid - 320) * 2048 + tid * 8;
    int c = idx >> 15;
    int rem = idx & 32767;
    int kk = rem >> 11;
    int rem2 = rem & 2047;
    int n = rem2 >> 5;
    int ep = rem2 & 31;
    int r = c >> 1, s = c & 1;
    unsigned short v[8];
#pragma unroll
    for (int j = 0; j < 8; j++) {
      int k = kk * 32 + ep + j;
      int tap = k >> 7, ic = k & 127;
      int dh = tap >> 1, dw = tap & 1;
      int kh = 3 - r - 2 * dh, kw = 3 - s - 2 * dw;
      v[j] = f2bf(w3[ic * 1024 + n * 16 + kh * 4 + kw]);
    }
    *(uint4*)(w3c + idx) = pack8(v);
  } else if (bid < 416) {
    // idle (w3c needs only 64 blocks; keep bid numbering stable)
  } else if (bid < 440) {
    // identp [b*3+ic][98][100]
    int bci = bid - 416;
    const float* src = ident + bci * 9216;
    unsigned short* dst = identp + bci * 9800;
    for (int i = tid; i < 9800; i += 256) {
      int row = i / 100, col = i - row * 100;
      bool in = (row >= 1) && (row <= 96) && (col >= 1) && (col <= 96);
      dst[i] = in ? f2bf(src[(row - 1) * 96 + (col - 1)]) : (unsigned short)0;
    }
  } else if (bid < 696) {
    // act1cl halo zero [50][52][64]
    unsigned short* base = act1cl + (size_t)(bid - 440) * 166400u;
    for (int c = tid; c < 1568; c += 256) {
      int cell = c >> 3, v = c & 7;
      int row, col;
      if (cell < 50) { row = 0; col = cell; }
      else if (cell < 100) { row = 49; col = cell - 50; }
      else if (cell < 148) { row = cell - 99; col = 0; }
      else { row = cell - 147; col = 49; }
      *(uint4*)(base + (row * 52 + col) * 64 + v * 8) = (uint4){0, 0, 0, 0};
    }
  } else if (bid < 952) {
    // act2p halo zero [26][26][128]
    uint4* b4p = (uint4*)(act2p + (size_t)(bid - 696) * 86528u);
    uint4 z = {0, 0, 0, 0};
    for (int c = tid; c < 1600; c += 256) {
      int cell = c >> 4, v = c & 15;
      int row, col;
      if (cell < 26) { row = 0; col = cell; }
      else if (cell < 52) { row = 25; col = cell - 26; }
      else if (cell < 76) { row = cell - 51; col = 0; }
      else { row = cell - 75; col = 25; }
      b4p[(row * 26 + col) * 16 + v] = z;
    }
  } else if (bid == 952) {
    // w1b [64 oc][64 k native]
    int e = tid * 16;
    unsigned short v[16];
#pragma unroll
    for (int q = 0; q < 4; q++) {
      float4 f = *(const float4*)(w1 + e + q * 4);
      v[q * 4 + 0] = f2bf(f.x); v[q * 4 + 1] = f2bf(f.y);
      v[q * 4 + 2] = f2bf(f.z); v[q * 4 + 3] = f2bf(f.w);
    }
    *(uint4*)(w1b + e) = pack8(v);
    *(uint4*)(w1b + e + 8) = pack8(v + 8);
  } else {
    // w4c [n16][k576]: k=(dh*3+dw)*64+ic; n=cls*3+oc
    for (int idx = tid; idx < 9216; idx += 256) {
      int n = idx / 576, k = idx - n * 576;
      int t = k >> 6, ic = k & 63;
      int dh = t / 3, dw = t - dh * 3;
      unsigned short val = 0;
      if (n < 12) {
        int cls = n / 3, oc = n - cls * 3;
        int r = cls >> 1, s = cls & 1;
        int a = r - dh + 1, b = s - dw + 1;
        if (a >= 0 && a < 2 && b >= 0 && b < 2) {
          int kh = 2 * a + 1 - r, kw = 2 * b + 1 - s;
          val = f2bf(w4[ic * 48 + oc * 16 + kh * 4 + kw]);
        }
      }
      w4c[idx] = val;
    }
  }
}

// ============ conv1 (MFMA, role-swapped): -> act1cl [50][52][64] ============
__global__ __launch_bounds__(256) void conv1_kernel(
    const unsigned short* __restrict__ identp, const unsigned short* __restrict__ hmp,
    const unsigned short* __restrict__ w1b, const float* __restrict__ b1,
    unsigned short* __restrict__ act1cl) {
  __shared__ unsigned short stage[4608];  // 4 waves x 16 px x 72
  int tid = threadIdx.x;
  int bx = blockIdx.x, bt = blockIdx.y;
  int b = bt >> 5;
  int wave = tid >> 6, lane = tid & 63, quad = lane >> 4, l16 = lane & 15;
  int px0 = bx * 64 + wave * 16;
  int pxa = px0 + l16;
  int oh = pxa / 48, ow = pxa % 48;

  floatx4 acc[4];
#pragma unroll
  for (int nt = 0; nt < 4; nt++) acc[nt] = (floatx4){0.f, 0.f, 0.f, 0.f};

#pragma unroll
  for (int kk = 0; kk < 2; kk++) {
    int k0 = kk * 32 + quad * 8;
    int ic = k0 >> 4, khp = (k0 >> 3) & 1;
    const unsigned short* src = (ic < 3) ? identp + (b * 3 + ic) * 9800
                                         : hmp + bt * 9800;
    const unsigned short* p = src + (2 * oh + khp * 2) * 100 + 2 * ow;
    UV a;
    a.u.x = *(const unsigned int*)(p);
    a.u.y = *(const unsigned int*)(p + 2);
    a.u.z = *(const unsigned int*)(p + 100);
    a.u.w = *(const unsigned int*)(p + 102);
#pragma unroll
    for (int nt = 0; nt < 4; nt++) {
      UV bv;
      bv.u = *(const uint4*)(w1b + (nt * 16 + l16) * 64 + kk * 32 + quad * 8);
      acc[nt] = __builtin_amdgcn_mfma_f32_16x16x32_bf16(a.s, bv.s, acc[nt], 0, 0, 0);
    }
  }

  float bias[4];
#pragma unroll
  for (int nt = 0; nt < 4; nt++) bias[nt] = b1[nt * 16 + l16];
  unsigned short* sw = stage + wave * 1152;
#pragma unroll
  for (int nt = 0; nt < 4; nt++)
#pragma unroll
    for (int reg = 0; reg < 4; reg++) {
      float v = fmaxf(acc[nt][reg] + bias[nt], 0.f);
      sw[(quad * 4 + reg) * 72 + nt * 16 + l16] = f2bf(v);
    }
  __syncthreads();
  int oh0 = px0 / 48, ow0 = px0 % 48;
  unsigned short* gout = act1cl + (size_t)bt * 166400u + ((oh0 + 1) * 52 + ow0 + 1) * 64;
#pragma unroll
  for (int it = 0; it < 8; it++) {
    int pl = it * 2 + (lane >> 5);
    unsigned int v = *(const unsigned int*)(sw + pl * 72 + (lane & 31) * 2);
    *(unsigned int*)(gout + pl * 64 + (lane & 31) * 2) = v;
  }
}

// ============ conv2 (MFMA, role-swapped): act1cl -> relu -> act2p [26][26][128] ============
__global__ __launch_bounds__(256, 2) void conv2_kernel(
    const unsigned short* __restrict__ act1cl, const unsigned short* __restrict__ w2t,
    const float* __restrict__ b2, unsigned short* __restrict__ act2p) {
  __shared__ unsigned short Blds[2][128 * 40];  // 20480 B
  int tid = threadIdx.x;
  int bx = blockIdx.x, bt = blockIdx.y;
  int wave = tid >> 6, lane = tid & 63, quad = lane >> 4, l16 = lane & 15;
  const unsigned short* frame = act1cl + (size_t)bt * 166400u;
  const unsigned short* abase[3];
#pragma unroll
  for (int mf = 0; mf < 3; mf++) {
    int px = bx * 192 + wave * 48 + mf * 16 + l16;
    int oh = px / 24, ow = px % 24;
    abase[mf] = frame + ((2 * oh) * 52 + 2 * ow) * 64 + quad * 8;
  }
  // contiguous weight staging: thread t reads w2t + kk*4096 + t*16 (lane-linear)
  const unsigned short* bptr = w2t + tid * 16;
  unsigned short* sdst = &Blds[0][0] + (tid >> 1) * 40 + (tid & 1) * 16;

  floatx4 acc[3][8];
#pragma unroll
  for (int mf = 0; mf < 3; mf++)
#pragma unroll
    for (int nt = 0; nt < 8; nt++) acc[mf][nt] = (floatx4){0.f, 0.f, 0.f, 0.f};

  {
    uint4 s0 = *(const uint4*)(bptr);
    uint4 s1 = *(const uint4*)(bptr + 8);
    *(uint4*)(sdst) = s0;
    *(uint4*)(sdst + 8) = s1;
  }
  UV a_cur[3], a_nxt[3];
#pragma unroll
  for (int mf = 0; mf < 3; mf++) a_cur[mf].u = *(const uint4*)(abase[mf]);
  __syncthreads();

#pragma unroll 2
  for (int kk = 0; kk < 32; kk++) {
    int cur = kk & 1;
    UV bf[8];
#pragma unroll
    for (int nt = 0; nt < 8; nt++)
      bf[nt].u = *(const uint4*)(&Blds[cur][(nt * 16 + l16) * 40 + quad * 8]);
    uint4 ns0, ns1;
    if (kk < 31) {
      const unsigned short* p = bptr + (kk + 1) * 4096;
      ns0 = *(const uint4*)(p);
      ns1 = *(const uint4*)(p + 8);
      int tap = (kk + 1) >> 1, ic0 = ((kk + 1) & 1) * 32;
      int kh = tap >> 2, kw = tap & 3;
      int aoff = (kh * 52 + kw) * 64 + ic0;
#pragma unroll
      for (int mf = 0; mf < 3; mf++) a_nxt[mf].u = *(const uint4*)(abase[mf] + aoff);
    }
#pragma unroll
    for (int mf = 0; mf < 3; mf++)
#pragma unroll
      for (int nt = 0; nt < 8; nt++)
        acc[mf][nt] = __builtin_amdgcn_mfma_f32_16x16x32_bf16(a_cur[mf].s, bf[nt].s, acc[mf][nt], 0, 0, 0);
    if (kk < 31) {
      unsigned short* d = sdst + (1 - cur) * 5120;
      *(uint4*)(d) = ns0;
      *(uint4*)(d + 8) = ns1;
    }
    __syncthreads();
#pragma unroll
    for (int mf = 0; mf < 3; mf++) a_cur[mf] = a_nxt[mf];
  }

  float bias[8];
#pragma unroll
  for (int nt = 0; nt < 8; nt++) bias[nt] = b2[nt * 16 + l16];
  unsigned short* sw = &Blds[0][0] + wave * 2176;  // 16 px x 136
  unsigned short* obase = act2p + (size_t)bt * 86528u;
#pragma unroll
  for (int mf = 0; mf < 3; mf++) {
#pragma unroll
    for (int nt = 0; nt < 8; nt++)
#pragma unroll
      for (int reg = 0; reg < 4; reg++) {
        float v = fmaxf(acc[mf][nt][reg] + bias[nt], 0.f);
        sw[(quad * 4 + reg) * 136 + nt * 16 + l16] = f2bf(v);
      }
    __syncthreads();
#pragma unroll
    for (int it = 0; it < 16; it++) {
      unsigned int v = *(const unsigned int*)(sw + it * 136 + lane * 2);
      int px = bx * 192 + wave * 48 + mf * 16 + it;
      int oh = px / 24, ow = px % 24;
      *(unsigned int*)(obase + ((oh + 1) * 26 + ow + 1) * 128 + lane * 2) = v;
    }
    __syncthreads();
  }
}

// ============ deconv3 v4 (4-parity, pad-40 LDS, two-slab staging, no per-kk barriers) ============
// Each block: one (r,s) parity class, 192 output px (8 out-rows x 24 cols), N=64 oc.
// K = 4 taps x 128 ic = 512 -> 16 kk of K=32. Class weights 64 KB staged in two 8-kk
// slabs, dense global -> LDS rows padded to 40 shorts (conv2's proven conflict fix).
// A prefetched 1 ahead in regs. Grid (12, 256): (c = x&3, bx = x>>2), y = bt.
__global__ __launch_bounds__(256) void deconv3_kernel(
    const unsigned short* __restrict__ act2p, const unsigned short* __restrict__ w3c,
    const float* __restrict__ b3, unsigned short* __restrict__ act3p) {
  __shared__ uint4 lds[2560];  // 40960 B: 8 kk x 64 n x 40 shorts; reused for out-staging
  int tid = threadIdx.x;
  int wave = tid >> 6, lane = tid & 63, quad = lane >> 4, l16 = lane & 15;

  int bxc = blockIdx.x, bt = blockIdx.y;
  int c = bxc & 3, bx = bxc >> 2;
  int r = c >> 1, s = c & 1;
  const unsigned short* a2 = act2p + (size_t)bt * 86528u;
  unsigned short* a3 = act3p + (size_t)bt * 160000u;

  // act3p halo zero (one block per frame; halo disjoint from interior writes)
  if (bxc == 0) {
    uint4* hz = (uint4*)a3;
    uint4 z = {0, 0, 0, 0};
    for (int cc = tid; cc < 1568; cc += 256) {
      int cell = cc >> 3, v = cc & 7;
      int row, col;
      if (cell < 50) { row = 0; col = cell; }
      else if (cell < 100) { row = 49; col = cell - 50; }
      else if (cell < 148) { row = cell - 99; col = 0; }
      else { row = cell - 147; col = 49; }
      hz[(row * 50 + col) * 8 + v] = z;
    }
  }

  const unsigned short* abase[3];
#pragma unroll
  for (int mf = 0; mf < 3; mf++) {
    int px = bx * 192 + wave * 48 + mf * 16 + l16;
    int i = px / 24, j = px - (px / 24) * 24;
    abase[mf] = a2 + ((i + r) * 26 + (j + s)) * 128 + quad * 8;
  }

  floatx4 acc[3][4];
#pragma unroll
  for (int mf = 0; mf < 3; mf++)
#pragma unroll
    for (int nt = 0; nt < 4; nt++) acc[mf][nt] = (floatx4){0.f, 0.f, 0.f, 0.f};

  const unsigned short* Bl = (const unsigned short*)lds;

  // stage slab0 (kk 0..7): dense global (4 uint4 per n-row) -> pad-40 LDS rows
  {
    const uint4* gw = (const uint4*)(w3c + c * 32768);
#pragma unroll
    for (int v = 0; v < 8; v++) {
      int g = v * 256 + tid;
      uint4 d = gw[g];
      int kkl = g >> 8, r8 = g & 255;
      int row = r8 >> 2, q = r8 & 3;
      lds[kkl * 320 + row * 5 + q] = d;
    }
  }
  UV a_cur[3], a_nxt[3];
#pragma unroll
  for (int mf = 0; mf < 3; mf++) a_cur[mf].u = *(const uint4*)(abase[mf]);  // kk=0: tap0, ic0=0
  __syncthreads();

#pragma unroll
  for (int half = 0; half < 2; half++) {
    if (half == 1) {
      __syncthreads();  // all waves done reading slab0
      const uint4* gw = (const uint4*)(w3c + c * 32768 + 16384);
#pragma unroll
      for (int v = 0; v < 8; v++) {
        int g = v * 256 + tid;
        uint4 d = gw[g];
        int kkl = g >> 8, r8 = g & 255;
        int row = r8 >> 2, q = r8 & 3;
        lds[kkl * 320 + row * 5 + q] = d;
      }
      __syncthreads();  // slab1 staged
    }
#pragma unroll
    for (int kl = 0; kl < 8; kl++) {
      int kk = half * 8 + kl;
      UV bf[4];
#pragma unroll
      for (int nt = 0; nt < 4; nt++)
        bf[nt].u = *(const uint4*)(Bl + kl * 2560 + (nt * 16 + l16) * 40 + quad * 8);
      if (kk < 15) {
        int kn = kk + 1;
        int tap = kn >> 2;
        int aoff = (((tap >> 1) * 26 + (tap & 1)) * 128) + (kn & 3) * 32;
#pragma unroll
        for (int mf = 0; mf < 3; mf++) a_nxt[mf].u = *(const uint4*)(abase[mf] + aoff);
      }
#pragma unroll
      for (int mf = 0; mf < 3; mf++)
#pragma unroll
        for (int nt = 0; nt < 4; nt++)
          acc[mf][nt] = __builtin_amdgcn_mfma_f32_16x16x32_bf16(a_cur[mf].s, bf[nt].s, acc[mf][nt], 0, 0, 0);
#pragma unroll
      for (int mf = 0; mf < 3; mf++) a_cur[mf] = a_nxt[mf];
    }
  }

  float bias[4];
#pragma unroll
  for (int nt = 0; nt < 4; nt++) bias[nt] = b3[nt * 16 + l16];

  __syncthreads();  // all waves done reading slab1 before staging reuse

  unsigned short* sw = (unsigned short*)lds + wave * 1152;  // 16 px x 72 (per-wave private)
#pragma unroll
  for (int mf = 0; mf < 3; mf++) {
#pragma unroll
    for (int nt = 0; nt < 4; nt++)
#pragma unroll
      for (int reg = 0; reg < 4; reg++) {
        float v = fmaxf(acc[mf][nt][reg] + bias[nt], 0.f);
        sw[(quad * 4 + reg) * 72 + nt * 16 + l16] = f2bf(v);
      }
    __syncthreads();
    int pxt = bx * 192 + wave * 48 + mf * 16;
#pragma unroll
    for (int it = 0; it < 8; it++) {
      int p = it * 2 + (lane >> 5);
      int px = pxt + p;
      int i = px / 24, j = px - (px / 24) * 24;
      unsigned int v = *(const unsigned int*)(sw + p * 72 + (lane & 31) * 2);
      *(unsigned int*)(a3 + ((2 * i + r + 1) * 50 + (2 * j + s + 1)) * 64 + (lane & 31) * 2) = v;
    }
    __syncthreads();
  }
}

// ============ deconv4 v3 (LDS-staged, contiguous loads) + tanh ============
// grid (12, 256): block stages act3p rows i0..i0+5 (chunk-rotated) + w4c into LDS
// with lane-linear uint4 copies; frags via ds_read_b128. Wave w = row i0+w, 3 tiles.
__global__ __launch_bounds__(256) void deconv4_kernel(
    const unsigned short* __restrict__ act3p, const unsigned short* __restrict__ w4c,
    const float* __restrict__ b4, float* __restrict__ out) {
  __shared__ uint4 lds4[2400 + 1168];  // 38400 B act rows + 18688 B w4c (rows padded to 73 uint4)
  int tid = threadIdx.x;
  int wave = tid >> 6, lane = tid & 63, quad = lane >> 4, l16 = lane & 15;
  int bx = blockIdx.x, bt = blockIdx.y;
  int i0 = bx * 4;

  // stage act3p rows i0..i0+5; record rec chunk lc -> physical (lc+rec)&7
  const uint4* src = (const uint4*)(act3p + (size_t)bt * 160000u + i0 * 3200);
#pragma unroll
  for (int v = 0; v < 10; v++) {
    int g = v * 256 + tid;
    if (g < 2400) {
      uint4 d = src[g];
      int row = g / 400;
      int rem = g - row * 400;
      int rec = rem >> 3, lc = rem & 7;
      lds4[row * 400 + rec * 8 + ((lc + rec) & 7)] = d;
    }
  }
  // stage w4c [16][576el] -> rows padded to 73 uint4 (1168 B)
  const uint4* wsrc = (const uint4*)w4c;
#pragma unroll
  for (int v = 0; v < 5; v++) {
    int g = v * 256 + tid;
    if (g < 1152) {
      uint4 d = wsrc[g];
      int n = g / 72, off = g - n * 72;
      lds4[2400 + n * 73 + off] = d;
    }
  }
  __syncthreads();

  const char* alds = (const char*)lds4;
  const char* blds = (const char*)(lds4 + 2400);

  // B-frags once per wave (reused across 3 tiles)
  UV bfr[18];
#pragma unroll
  for (int kk = 0; kk < 18; kk++)
    bfr[kk].u = *(const uint4*)(blds + l16 * 1168 + kk * 64 + quad * 16);

  int i = i0 + wave;  // input row 0..47
  int n = l16;
  int cls = n / 3, oc = n - cls * 3;
  int r = cls >> 1, s = cls & 1;
  float bias = (n < 12) ? b4[oc] : 0.f;
  int oh = 2 * i + r;

#pragma unroll
  for (int t3 = 0; t3 < 3; t3++) {
    int j0 = t3 * 16;
    floatx4 acc = (floatx4){0.f, 0.f, 0.f, 0.f};
#pragma unroll
    for (int kk = 0; kk < 18; kk++) {
      int par = kk & 1, tap = kk >> 1;
      int dh = tap / 3, dw = tap - dh * 3;
      int rec = j0 + dw + l16;
      int pc = (par * 4 + quad + rec) & 7;
      UV a;
      a.u = *(const uint4*)(alds + (wave + dh) * 6400 + rec * 128 + pc * 16);
      acc = __builtin_amdgcn_mfma_f32_16x16x32_bf16(a.s, bfr[kk].s, acc, 0, 0, 0);
    }
    if (n < 12) {
      float* obase = out + (size_t)bt * 27648u + oc * 9216 + oh * 96 + s;
#pragma unroll
      for (int reg = 0; reg < 4; reg++) {
        int jj = j0 + quad * 4 + reg;
        obase[2 * jj] = ftanh(acc[reg] + bias);
      }
    }
  }
}

extern "C" void kernel_launch(void* const* d_in, const int* in_sizes, int n_in,
                              void* d_out, int out_size, void* d_ws, size_t ws_size,
                              hipStream_t stream) {
  const float* ident = (const float*)d_in[0];
  const float* lm = (const float*)d_in[1];
  const float* w1 = (const float*)d_in[2];
  const float* b1 = (const float*)d_in[3];
  const float* w2 = (const float*)d_in[4];
  const float* b2 = (const float*)d_in[5];
  const float* w3 = (const float*)d_in[6];
  const float* b3 = (const float*)d_in[7];
  const float* w4 = (const float*)d_in[8];
  const float* b4 = (const float*)d_in[9];
  float* out = (float*)d_out;
  char* ws = (char*)d_ws;
  unsigned short* identp = (unsigned short*)(ws + IDENTP_OFF);
  unsigned short* hmp = (unsigned short*)(ws + HMP_OFF);
  unsigned short* act1cl = (unsigned short*)(ws + ACT1CL_OFF);
  unsigned short* act2p = (unsigned short*)(ws + ACT2P_OFF);
  unsigned short* act3p = (unsigned short*)(ws + ACT3P_OFF);
  unsigned short* w2t = (unsigned short*)(ws + W2B_OFF);
  unsigned short* w3c = (unsigned short*)(ws + W3B_OFF);
  unsigned short* w1b = (unsigned short*)(ws + W1B_OFF);
  unsigned short* w4c = (unsigned short*)(ws + W4C_OFF);

  prep_kernel<<<dim3(954), 256, 0, stream>>>(lm, ident, w1, w2, w3, w4, identp, hmp,
                                             w1b, w2t, w3c, w4c, act1cl, act2p);
  conv1_kernel<<<dim3(36, 256), 256, 0, stream>>>(identp, hmp, w1b, b1, act1cl);
  conv2_kernel<<<dim3(3, 256), 256, 0, stream>>>(act1cl, w2t, b2, act2p);
  deconv3_kernel<<<dim3(12, 256), 256, 0, stream>>>(act2p, w3c, b3, act3p);
  deconv4_kernel<<<dim3(12, 256), 256, 0, stream>>>(act3p, w4c, b4, out);
}

// Round 4
// 320.570 us; speedup vs baseline: 1.0129x; 1.0129x over previous
//
#include <hip/hip_runtime.h>

// ---- workspace layout (bytes) ----
#define IDENTP_OFF 0u            // identp: 8*3*98*100*2 = 470400
#define HMP_OFF    470400u       // hmp: 256*98*100*2 = 5017600
#define ACT1CL_OFF 5488000u      // act1cl: 256*50*52*64*2 = 85196800 (ends 90684800)
#define ACT3P_OFF  470400u       // act3p: 256*50*50*64*2 = 81920000 — aliases hmp+act1cl (dead after conv2)
#define ACT2P_OFF  90684800u     // act2p: 256*26*26*128*2 = 44302336
#define W2B_OFF    134987136u    // w2t: [32 kk][128n*32el] = 262144
#define W3B_OFF    135249280u    // w3c: [4 cls][16 kk][64n][32e linear] = 262144
#define W1B_OFF    135642496u    // w1b: 64*64*2 = 8192
#define W4C_OFF    135650688u    // w4c: 16*576*2 = 18432

using short8  = __attribute__((ext_vector_type(8))) short;
using floatx4 = __attribute__((ext_vector_type(4))) float;
union UV { uint4 u; short8 s; };

static __device__ __forceinline__ float bf2f(unsigned short u) {
  union { unsigned int i; float f; } v; v.i = ((unsigned int)u) << 16; return v.f;
}
static __device__ __forceinline__ unsigned short f2bf(float f) {
  union { float f; unsigned int i; } v; v.f = f;
  unsigned int x = v.i;
  return (unsigned short)((x + 0x7FFFu + ((x >> 16) & 1u)) >> 16);  // RNE
}
static __device__ __forceinline__ uint4 pack8(const unsigned short* v) {
  uint4 p;
  p.x = (unsigned)v[0] | ((unsigned)v[1] << 16);
  p.y = (unsigned)v[2] | ((unsigned)v[3] << 16);
  p.z = (unsigned)v[4] | ((unsigned)v[5] << 16);
  p.w = (unsigned)v[6] | ((unsigned)v[7] << 16);
  return p;
}
static __device__ __forceinline__ float ftanh(float x) {
  x = fminf(fmaxf(x, -10.f), 10.f);
  float e = __expf(2.f * x);
  return (e - 1.f) * __builtin_amdgcn_rcpf(e + 1.f);
}

// ============ prep ============
__global__ __launch_bounds__(256) void prep_kernel(
    const float* __restrict__ lm, const float* __restrict__ ident,
    const float* __restrict__ w1, const float* __restrict__ w2,
    const float* __restrict__ w3, const float* __restrict__ w4,
    unsigned short* __restrict__ identp, unsigned short* __restrict__ hmp,
    unsigned short* __restrict__ w1b, unsigned short* __restrict__ w2t,
    unsigned short* __restrict__ w3c, unsigned short* __restrict__ w4c,
    unsigned short* __restrict__ act1cl, unsigned short* __restrict__ act2p) {
  int bid = blockIdx.x, tid = threadIdx.x;
  if (bid < 256) {
    // hmp [bt][98][100]
    unsigned int* h32 = (unsigned int*)(hmp + bid * 9800);
    for (int i = tid; i < 4900; i += 256) h32[i] = 0u;
    __syncthreads();
    if (tid < 68) {
      float x = lm[bid * 136 + tid * 2 + 0] * 95.0f;
      float y = lm[bid * 136 + tid * 2 + 1] * 95.0f;
      int ix = (int)x, iy = (int)y;
      if (ix >= 0 && ix < 96 && iy >= 0 && iy < 96)
        hmp[bid * 9800 + (iy + 1) * 100 + (ix + 1)] = 0x3F80;
    }
  } else if (bid < 320) {
    // w2t [kk32][n128*32el]: element (kk,n,e): k'=kk*32+e, k'=tap*64+ic
    int idx = (bid - 256) * 2048 + tid * 8;
    int kk = idx >> 12, rem = idx & 4095;
    int n = rem >> 5, e = rem & 31;
    unsigned short v[8];
#pragma unroll
    for (int j = 0; j < 8; j++) {
      int t = kk * 32 + e + j;
      int tap = t >> 6, ic = t & 63;
      v[j] = f2bf(w2[n * 1024 + ic * 16 + tap]);
    }
    *(uint4*)(w2t + idx) = pack8(v);
  } else if (bid < 384) {
    // w3c [4 cls][16 kk][64 n][32 e] LINEAR: k = kk*32+e; tap=k>>7 (dh=tap>>1,dw=tap&1); ic=k&127
    //   kh = 3 - r - 2*dh, kw = 3 - s - 2*dw   (all taps valid -> zero-free)
    int idx = (bid - 320) * 2048 + tid * 8;
    int c = idx >> 15;
    int rem = idx & 32767;
    int kk = rem >> 11;
    int rem2 = rem & 2047;
    int n = rem2 >> 5;
    int ep = rem2 & 31;
    int r = c >> 1, s = c & 1;
    unsigned short v[8];
#pragma unroll
    for (int j = 0; j < 8; j++) {
      int k = kk * 32 + ep + j;
      int tap = k >> 7, ic = k & 127;
      int dh = tap >> 1, dw = tap & 1;
      int kh = 3 - r - 2 * dh, kw = 3 - s - 2 * dw;
      v[j] = f2bf(w3[ic * 1024 + n * 16 + kh * 4 + kw]);
    }
    *(uint4*)(w3c + idx) = pack8(v);
  } else if (bid < 416) {
    // idle (w3c needs only 64 blocks; keep bid numbering stable)
  } else if (bid < 440) {
    // identp [b*3+ic][98][100]
    int bci = bid - 416;
    const float* src = ident + bci * 9216;
    unsigned short* dst = identp + bci * 9800;
    for (int i = tid; i < 9800; i += 256) {
      int row = i / 100, col = i - row * 100;
      bool in = (row >= 1) && (row <= 96) && (col >= 1) && (col <= 96);
      dst[i] = in ? f2bf(src[(row - 1) * 96 + (col - 1)]) : (unsigned short)0;
    }
  } else if (bid < 696) {
    // act1cl halo zero [50][52][64]
    unsigned short* base = act1cl + (size_t)(bid - 440) * 166400u;
    for (int c = tid; c < 1568; c += 256) {
      int cell = c >> 3, v = c & 7;
      int row, col;
      if (cell < 50) { row = 0; col = cell; }
      else if (cell < 100) { row = 49; col = cell - 50; }
      else if (cell < 148) { row = cell - 99; col = 0; }
      else { row = cell - 147; col = 49; }
      *(uint4*)(base + (row * 52 + col) * 64 + v * 8) = (uint4){0, 0, 0, 0};
    }
  } else if (bid < 952) {
    // act2p halo zero [26][26][128]
    uint4* b4p = (uint4*)(act2p + (size_t)(bid - 696) * 86528u);
    uint4 z = {0, 0, 0, 0};
    for (int c = tid; c < 1600; c += 256) {
      int cell = c >> 4, v = c & 15;
      int row, col;
      if (cell < 26) { row = 0; col = cell; }
      else if (cell < 52) { row = 25; col = cell - 26; }
      else if (cell < 76) { row = cell - 51; col = 0; }
      else { row = cell - 75; col = 25; }
      b4p[(row * 26 + col) * 16 + v] = z;
    }
  } else if (bid == 952) {
    // w1b [64 oc][64 k native]
    int e = tid * 16;
    unsigned short v[16];
#pragma unroll
    for (int q = 0; q < 4; q++) {
      float4 f = *(const float4*)(w1 + e + q * 4);
      v[q * 4 + 0] = f2bf(f.x); v[q * 4 + 1] = f2bf(f.y);
      v[q * 4 + 2] = f2bf(f.z); v[q * 4 + 3] = f2bf(f.w);
    }
    *(uint4*)(w1b + e) = pack8(v);
    *(uint4*)(w1b + e + 8) = pack8(v + 8);
  } else {
    // w4c [n16][k576]: k=(dh*3+dw)*64+ic; n=cls*3+oc
    for (int idx = tid; idx < 9216; idx += 256) {
      int n = idx / 576, k = idx - n * 576;
      int t = k >> 6, ic = k & 63;
      int dh = t / 3, dw = t - dh * 3;
      unsigned short val = 0;
      if (n < 12) {
        int cls = n / 3, oc = n - cls * 3;
        int r = cls >> 1, s = cls & 1;
        int a = r - dh + 1, b = s - dw + 1;
        if (a >= 0 && a < 2 && b >= 0 && b < 2) {
          int kh = 2 * a + 1 - r, kw = 2 * b + 1 - s;
          val = f2bf(w4[ic * 48 + oc * 16 + kh * 4 + kw]);
        }
      }
      w4c[idx] = val;
    }
  }
}

// ============ conv1 (MFMA, role-swapped): -> act1cl [50][52][64] ============
__global__ __launch_bounds__(256) void conv1_kernel(
    const unsigned short* __restrict__ identp, const unsigned short* __restrict__ hmp,
    const unsigned short* __restrict__ w1b, const float* __restrict__ b1,
    unsigned short* __restrict__ act1cl) {
  __shared__ unsigned short stage[4608];  // 4 waves x 16 px x 72
  int tid = threadIdx.x;
  int bx = blockIdx.x, bt = blockIdx.y;
  int b = bt >> 5;
  int wave = tid >> 6, lane = tid & 63, quad = lane >> 4, l16 = lane & 15;
  int px0 = bx * 64 + wave * 16;
  int pxa = px0 + l16;
  int oh = pxa / 48, ow = pxa % 48;

  floatx4 acc[4];
#pragma unroll
  for (int nt = 0; nt < 4; nt++) acc[nt] = (floatx4){0.f, 0.f, 0.f, 0.f};

#pragma unroll
  for (int kk = 0; kk < 2; kk++) {
    int k0 = kk * 32 + quad * 8;
    int ic = k0 >> 4, khp = (k0 >> 3) & 1;
    const unsigned short* src = (ic < 3) ? identp + (b * 3 + ic) * 9800
                                         : hmp + bt * 9800;
    const unsigned short* p = src + (2 * oh + khp * 2) * 100 + 2 * ow;
    UV a;
    a.u.x = *(const unsigned int*)(p);
    a.u.y = *(const unsigned int*)(p + 2);
    a.u.z = *(const unsigned int*)(p + 100);
    a.u.w = *(const unsigned int*)(p + 102);
#pragma unroll
    for (int nt = 0; nt < 4; nt++) {
      UV bv;
      bv.u = *(const uint4*)(w1b + (nt * 16 + l16) * 64 + kk * 32 + quad * 8);
      acc[nt] = __builtin_amdgcn_mfma_f32_16x16x32_bf16(a.s, bv.s, acc[nt], 0, 0, 0);
    }
  }

  float bias[4];
#pragma unroll
  for (int nt = 0; nt < 4; nt++) bias[nt] = b1[nt * 16 + l16];
  unsigned short* sw = stage + wave * 1152;
#pragma unroll
  for (int nt = 0; nt < 4; nt++)
#pragma unroll
    for (int reg = 0; reg < 4; reg++) {
      float v = fmaxf(acc[nt][reg] + bias[nt], 0.f);
      sw[(quad * 4 + reg) * 72 + nt * 16 + l16] = f2bf(v);
    }
  __syncthreads();
  int oh0 = px0 / 48, ow0 = px0 % 48;
  unsigned short* gout = act1cl + (size_t)bt * 166400u + ((oh0 + 1) * 52 + ow0 + 1) * 64;
#pragma unroll
  for (int it = 0; it < 8; it++) {
    int pl = it * 2 + (lane >> 5);
    unsigned int v = *(const unsigned int*)(sw + pl * 72 + (lane & 31) * 2);
    *(unsigned int*)(gout + pl * 64 + (lane & 31) * 2) = v;
  }
}

// ============ conv2 (MFMA, role-swapped): act1cl -> relu -> act2p [26][26][128] ============
__global__ __launch_bounds__(256, 2) void conv2_kernel(
    const unsigned short* __restrict__ act1cl, const unsigned short* __restrict__ w2t,
    const float* __restrict__ b2, unsigned short* __restrict__ act2p) {
  __shared__ unsigned short Blds[2][128 * 40];  // 20480 B
  int tid = threadIdx.x;
  int bx = blockIdx.x, bt = blockIdx.y;
  int wave = tid >> 6, lane = tid & 63, quad = lane >> 4, l16 = lane & 15;
  const unsigned short* frame = act1cl + (size_t)bt * 166400u;
  const unsigned short* abase[3];
#pragma unroll
  for (int mf = 0; mf < 3; mf++) {
    int px = bx * 192 + wave * 48 + mf * 16 + l16;
    int oh = px / 24, ow = px % 24;
    abase[mf] = frame + ((2 * oh) * 52 + 2 * ow) * 64 + quad * 8;
  }
  // contiguous weight staging: thread t reads w2t + kk*4096 + t*16 (lane-linear)
  const unsigned short* bptr = w2t + tid * 16;
  unsigned short* sdst = &Blds[0][0] + (tid >> 1) * 40 + (tid & 1) * 16;

  floatx4 acc[3][8];
#pragma unroll
  for (int mf = 0; mf < 3; mf++)
#pragma unroll
    for (int nt = 0; nt < 8; nt++) acc[mf][nt] = (floatx4){0.f, 0.f, 0.f, 0.f};

  {
    uint4 s0 = *(const uint4*)(bptr);
    uint4 s1 = *(const uint4*)(bptr + 8);
    *(uint4*)(sdst) = s0;
    *(uint4*)(sdst + 8) = s1;
  }
  UV a_cur[3], a_nxt[3];
#pragma unroll
  for (int mf = 0; mf < 3; mf++) a_cur[mf].u = *(const uint4*)(abase[mf]);
  __syncthreads();

#pragma unroll 2
  for (int kk = 0; kk < 32; kk++) {
    int cur = kk & 1;
    UV bf[8];
#pragma unroll
    for (int nt = 0; nt < 8; nt++)
      bf[nt].u = *(const uint4*)(&Blds[cur][(nt * 16 + l16) * 40 + quad * 8]);
    uint4 ns0, ns1;
    if (kk < 31) {
      const unsigned short* p = bptr + (kk + 1) * 4096;
      ns0 = *(const uint4*)(p);
      ns1 = *(const uint4*)(p + 8);
      int tap = (kk + 1) >> 1, ic0 = ((kk + 1) & 1) * 32;
      int kh = tap >> 2, kw = tap & 3;
      int aoff = (kh * 52 + kw) * 64 + ic0;
#pragma unroll
      for (int mf = 0; mf < 3; mf++) a_nxt[mf].u = *(const uint4*)(abase[mf] + aoff);
    }
#pragma unroll
    for (int mf = 0; mf < 3; mf++)
#pragma unroll
      for (int nt = 0; nt < 8; nt++)
        acc[mf][nt] = __builtin_amdgcn_mfma_f32_16x16x32_bf16(a_cur[mf].s, bf[nt].s, acc[mf][nt], 0, 0, 0);
    if (kk < 31) {
      unsigned short* d = sdst + (1 - cur) * 5120;
      *(uint4*)(d) = ns0;
      *(uint4*)(d + 8) = ns1;
    }
    __syncthreads();
#pragma unroll
    for (int mf = 0; mf < 3; mf++) a_cur[mf] = a_nxt[mf];
  }

  float bias[8];
#pragma unroll
  for (int nt = 0; nt < 8; nt++) bias[nt] = b2[nt * 16 + l16];
  unsigned short* sw = &Blds[0][0] + wave * 2176;  // 16 px x 136
  unsigned short* obase = act2p + (size_t)bt * 86528u;
#pragma unroll
  for (int mf = 0; mf < 3; mf++) {
#pragma unroll
    for (int nt = 0; nt < 8; nt++)
#pragma unroll
      for (int reg = 0; reg < 4; reg++) {
        float v = fmaxf(acc[mf][nt][reg] + bias[nt], 0.f);
        sw[(quad * 4 + reg) * 136 + nt * 16 + l16] = f2bf(v);
      }
    __syncthreads();
#pragma unroll
    for (int it = 0; it < 16; it++) {
      unsigned int v = *(const unsigned int*)(sw + it * 136 + lane * 2);
      int px = bx * 192 + wave * 48 + mf * 16 + it;
      int oh = px / 24, ow = px % 24;
      *(unsigned int*)(obase + ((oh + 1) * 26 + ow + 1) * 128 + lane * 2) = v;
    }
    __syncthreads();
  }
}

// ============ deconv3 v5 (4-parity, pad-40 LDS, two-slab staging, XCD-swizzled grid) ============
// Each block: one (r,s) parity class, 192 output px (8 out-rows x 24 cols), N=64 oc.
// K = 4 taps x 128 ic = 512 -> 16 kk of K=32. Class weights 64 KB staged in two 8-kk
// slabs, dense global -> LDS rows padded to 40 shorts. A prefetched 1 ahead in regs.
// Grid dim3(3072), bijective XCD swizzle: all 12 blocks of a frame land on one XCD
// so the 13.6x act2p read-overlap + 256 KB weights hit that XCD's L2 instead of HBM.
__global__ __launch_bounds__(256) void deconv3_kernel(
    const unsigned short* __restrict__ act2p, const unsigned short* __restrict__ w3c,
    const float* __restrict__ b3, unsigned short* __restrict__ act3p) {
  __shared__ uint4 lds[2560];  // 40960 B: 8 kk x 64 n x 40 shorts; reused for out-staging
  int tid = threadIdx.x;
  int wave = tid >> 6, lane = tid & 63, quad = lane >> 4, l16 = lane & 15;

  // XCD swizzle: hw round-robins consecutive bid across 8 XCDs; give XCD k a
  // contiguous logical chunk. bijective: logical = (bid&7)*384 + (bid>>3).
  int bid = blockIdx.x;
  int logical = (bid & 7) * 384 + (bid >> 3);
  int bt = logical / 12;
  int rem = logical - bt * 12;
  int c = rem & 3, bx = rem >> 2;
  int r = c >> 1, s = c & 1;
  const unsigned short* a2 = act2p + (size_t)bt * 86528u;
  unsigned short* a3 = act3p + (size_t)bt * 160000u;

  // act3p halo zero (one block per frame; halo disjoint from interior writes)
  if (rem == 0) {
    uint4* hz = (uint4*)a3;
    uint4 z = {0, 0, 0, 0};
    for (int cc = tid; cc < 1568; cc += 256) {
      int cell = cc >> 3, v = cc & 7;
      int row, col;
      if (cell < 50) { row = 0; col = cell; }
      else if (cell < 100) { row = 49; col = cell - 50; }
      else if (cell < 148) { row = cell - 99; col = 0; }
      else { row = cell - 147; col = 49; }
      hz[(row * 50 + col) * 8 + v] = z;
    }
  }

  const unsigned short* abase[3];
#pragma unroll
  for (int mf = 0; mf < 3; mf++) {
    int px = bx * 192 + wave * 48 + mf * 16 + l16;
    int i = px / 24, j = px - (px / 24) * 24;
    abase[mf] = a2 + ((i + r) * 26 + (j + s)) * 128 + quad * 8;
  }

  floatx4 acc[3][4];
#pragma unroll
  for (int mf = 0; mf < 3; mf++)
#pragma unroll
    for (int nt = 0; nt < 4; nt++) acc[mf][nt] = (floatx4){0.f, 0.f, 0.f, 0.f};

  const unsigned short* Bl = (const unsigned short*)lds;

  // stage slab0 (kk 0..7): dense global (4 uint4 per n-row) -> pad-40 LDS rows
  {
    const uint4* gw = (const uint4*)(w3c + c * 32768);
#pragma unroll
    for (int v = 0; v < 8; v++) {
      int g = v * 256 + tid;
      uint4 d = gw[g];
      int kkl = g >> 8, r8 = g & 255;
      int row = r8 >> 2, q = r8 & 3;
      lds[kkl * 320 + row * 5 + q] = d;
    }
  }
  UV a_cur[3], a_nxt[3];
#pragma unroll
  for (int mf = 0; mf < 3; mf++) a_cur[mf].u = *(const uint4*)(abase[mf]);  // kk=0: tap0, ic0=0
  __syncthreads();

#pragma unroll
  for (int half = 0; half < 2; half++) {
    if (half == 1) {
      __syncthreads();  // all waves done reading slab0
      const uint4* gw = (const uint4*)(w3c + c * 32768 + 16384);
#pragma unroll
      for (int v = 0; v < 8; v++) {
        int g = v * 256 + tid;
        uint4 d = gw[g];
        int kkl = g >> 8, r8 = g & 255;
        int row = r8 >> 2, q = r8 & 3;
        lds[kkl * 320 + row * 5 + q] = d;
      }
      __syncthreads();  // slab1 staged
    }
#pragma unroll
    for (int kl = 0; kl < 8; kl++) {
      int kk = half * 8 + kl;
      UV bf[4];
#pragma unroll
      for (int nt = 0; nt < 4; nt++)
        bf[nt].u = *(const uint4*)(Bl + kl * 2560 + (nt * 16 + l16) * 40 + quad * 8);
      if (kk < 15) {
        int kn = kk + 1;
        int tap = kn >> 2;
        int aoff = (((tap >> 1) * 26 + (tap & 1)) * 128) + (kn & 3) * 32;
#pragma unroll
        for (int mf = 0; mf < 3; mf++) a_nxt[mf].u = *(const uint4*)(abase[mf] + aoff);
      }
#pragma unroll
      for (int mf = 0; mf < 3; mf++)
#pragma unroll
        for (int nt = 0; nt < 4; nt++)
          acc[mf][nt] = __builtin_amdgcn_mfma_f32_16x16x32_bf16(a_cur[mf].s, bf[nt].s, acc[mf][nt], 0, 0, 0);
#pragma unroll
      for (int mf = 0; mf < 3; mf++) a_cur[mf] = a_nxt[mf];
    }
  }

  float bias[4];
#pragma unroll
  for (int nt = 0; nt < 4; nt++) bias[nt] = b3[nt * 16 + l16];

  __syncthreads();  // all waves done reading slab1 before staging reuse

  unsigned short* sw = (unsigned short*)lds + wave * 1152;  // 16 px x 72 (per-wave private)
#pragma unroll
  for (int mf = 0; mf < 3; mf++) {
#pragma unroll
    for (int nt = 0; nt < 4; nt++)
#pragma unroll
      for (int reg = 0; reg < 4; reg++) {
        float v = fmaxf(acc[mf][nt][reg] + bias[nt], 0.f);
        sw[(quad * 4 + reg) * 72 + nt * 16 + l16] = f2bf(v);
      }
    __syncthreads();
    int pxt = bx * 192 + wave * 48 + mf * 16;
#pragma unroll
    for (int it = 0; it < 8; it++) {
      int p = it * 2 + (lane >> 5);
      int px = pxt + p;
      int i = px / 24, j = px - (px / 24) * 24;
      unsigned int v = *(const unsigned int*)(sw + p * 72 + (lane & 31) * 2);
      *(unsigned int*)(a3 + ((2 * i + r + 1) * 50 + (2 * j + s + 1)) * 64 + (lane & 31) * 2) = v;
    }
    __syncthreads();
  }
}

// ============ deconv4 v3 (LDS-staged, contiguous loads) + tanh ============
// grid (12, 256): block stages act3p rows i0..i0+5 (chunk-rotated) + w4c into LDS
// with lane-linear uint4 copies; frags via ds_read_b128. Wave w = row i0+w, 3 tiles.
__global__ __launch_bounds__(256) void deconv4_kernel(
    const unsigned short* __restrict__ act3p, const unsigned short* __restrict__ w4c,
    const float* __restrict__ b4, float* __restrict__ out) {
  __shared__ uint4 lds4[2400 + 1168];  // 38400 B act rows + 18688 B w4c (rows padded to 73 uint4)
  int tid = threadIdx.x;
  int wave = tid >> 6, lane = tid & 63, quad = lane >> 4, l16 = lane & 15;
  int bx = blockIdx.x, bt = blockIdx.y;
  int i0 = bx * 4;

  // stage act3p rows i0..i0+5; record rec chunk lc -> physical (lc+rec)&7
  const uint4* src = (const uint4*)(act3p + (size_t)bt * 160000u + i0 * 3200);
#pragma unroll
  for (int v = 0; v < 10; v++) {
    int g = v * 256 + tid;
    if (g < 2400) {
      uint4 d = src[g];
      int row = g / 400;
      int rem = g - row * 400;
      int rec = rem >> 3, lc = rem & 7;
      lds4[row * 400 + rec * 8 + ((lc + rec) & 7)] = d;
    }
  }
  // stage w4c [16][576el] -> rows padded to 73 uint4 (1168 B)
  const uint4* wsrc = (const uint4*)w4c;
#pragma unroll
  for (int v = 0; v < 5; v++) {
    int g = v * 256 + tid;
    if (g < 1152) {
      uint4 d = wsrc[g];
      int n = g / 72, off = g - n * 72;
      lds4[2400 + n * 73 + off] = d;
    }
  }
  __syncthreads();

  const char* alds = (const char*)lds4;
  const char* blds = (const char*)(lds4 + 2400);

  // B-frags once per wave (reused across 3 tiles)
  UV bfr[18];
#pragma unroll
  for (int kk = 0; kk < 18; kk++)
    bfr[kk].u = *(const uint4*)(blds + l16 * 1168 + kk * 64 + quad * 16);

  int i = i0 + wave;  // input row 0..47
  int n = l16;
  int cls = n / 3, oc = n - cls * 3;
  int r = cls >> 1, s = cls & 1;
  float bias = (n < 12) ? b4[oc] : 0.f;
  int oh = 2 * i + r;

#pragma unroll
  for (int t3 = 0; t3 < 3; t3++) {
    int j0 = t3 * 16;
    floatx4 acc = (floatx4){0.f, 0.f, 0.f, 0.f};
#pragma unroll
    for (int kk = 0; kk < 18; kk++) {
      int par = kk & 1, tap = kk >> 1;
      int dh = tap / 3, dw = tap - dh * 3;
      int rec = j0 + dw + l16;
      int pc = (par * 4 + quad + rec) & 7;
      UV a;
      a.u = *(const uint4*)(alds + (wave + dh) * 6400 + rec * 128 + pc * 16);
      acc = __builtin_amdgcn_mfma_f32_16x16x32_bf16(a.s, bfr[kk].s, acc, 0, 0, 0);
    }
    if (n < 12) {
      float* obase = out + (size_t)bt * 27648u + oc * 9216 + oh * 96 + s;
#pragma unroll
      for (int reg = 0; reg < 4; reg++) {
        int jj = j0 + quad * 4 + reg;
        obase[2 * jj] = ftanh(acc[reg] + bias);
      }
    }
  }
}

extern "C" void kernel_launch(void* const* d_in, const int* in_sizes, int n_in,
                              void* d_out, int out_size, void* d_ws, size_t ws_size,
                              hipStream_t stream) {
  const float* ident = (const float*)d_in[0];
  const float* lm = (const float*)d_in[1];
  const float* w1 = (const float*)d_in[2];
  const float* b1 = (const float*)d_in[3];
  const float* w2 = (const float*)d_in[4];
  const float* b2 = (const float*)d_in[5];
  const float* w3 = (const float*)d_in[6];
  const float* b3 = (const float*)d_in[7];
  const float* w4 = (const float*)d_in[8];
  const float* b4 = (const float*)d_in[9];
  float* out = (float*)d_out;
  char* ws = (char*)d_ws;
  unsigned short* identp = (unsigned short*)(ws + IDENTP_OFF);
  unsigned short* hmp = (unsigned short*)(ws + HMP_OFF);
  unsigned short* act1cl = (unsigned short*)(ws + ACT1CL_OFF);
  unsigned short* act2p = (unsigned short*)(ws + ACT2P_OFF);
  unsigned short* act3p = (unsigned short*)(ws + ACT3P_OFF);
  unsigned short* w2t = (unsigned short*)(ws + W2B_OFF);
  unsigned short* w3c = (unsigned short*)(ws + W3B_OFF);
  unsigned short* w1b = (unsigned short*)(ws + W1B_OFF);
  unsigned short* w4c = (unsigned short*)(ws + W4C_OFF);

  prep_kernel<<<dim3(954), 256, 0, stream>>>(lm, ident, w1, w2, w3, w4, identp, hmp,
                                             w1b, w2t, w3c, w4c, act1cl, act2p);
  conv1_kernel<<<dim3(36, 256), 256, 0, stream>>>(identp, hmp, w1b, b1, act1cl);
  conv2_kernel<<<dim3(3, 256), 256, 0, stream>>>(act1cl, w2t, b2, act2p);
  deconv3_kernel<<<dim3(3072), 256, 0, stream>>>(act2p, w3c, b3, act3p);
  deconv4_kernel<<<dim3(12, 256), 256, 0, stream>>>(act3p, w4c, b4, out);
}